// Round 1
// baseline (1327.267 us; speedup 1.0000x reference)
//
#include <hip/hip_runtime.h>

// Problem constants (fixed by the reference file)
constexpr int B_   = 8;
constexpr int CIN  = 512;
constexpr int COUT = 3;
constexpr int WDIM = 512;
constexpr int HW   = 256 * 256;        // 65536 pixels per plane
constexpr float CLAMP_V = 256.0f;
constexpr float GAIN = 0.04419417382415922f;  // 1/sqrt(512)

// Kernel 1: m[b][o][c] = weight[o][c] * styles[b][c]
// styles[b][c] = (dot(w[b,:], affine_w[c,:]) * GAIN + affine_b[c]) * GAIN
// One wave (64 lanes) per (b,c) pair: 4096 waves total.
__global__ __launch_bounds__(256)
void styles_kernel(const float* __restrict__ w,        // (B, WDIM)
                   const float* __restrict__ weight,   // (COUT, CIN)
                   const float* __restrict__ affine_b, // (CIN,)
                   const float* __restrict__ affine_w, // (CIN, WDIM)
                   float* __restrict__ m)              // (B, COUT, CIN)
{
    const int gtid = blockIdx.x * blockDim.x + threadIdx.x;
    const int wid  = gtid >> 6;          // global wave id, 0..B*CIN-1
    const int lane = threadIdx.x & 63;
    const int b = wid >> 9;              // wid / CIN
    const int c = wid & (CIN - 1);       // wid % CIN

    const float* wr = w + b * WDIM;
    const float* ar = affine_w + (size_t)c * WDIM;

    float acc = 0.0f;
#pragma unroll
    for (int j = 0; j < WDIM / 64; ++j) {
        const int d = lane + 64 * j;     // coalesced across lanes
        acc += wr[d] * ar[d];
    }
    // 64-lane butterfly reduction — every lane ends with the full sum
#pragma unroll
    for (int off = 32; off >= 1; off >>= 1)
        acc += __shfl_xor(acc, off, 64);

    const float style = (acc * GAIN + affine_b[c]) * GAIN;

    if (lane < COUT) {
        const int o = lane;
        m[(b * COUT + o) * CIN + c] = weight[o * CIN + c] * style;
    }
}

// Kernel 2: out[b][o][pix] = clamp(sum_c x[b][c][pix] * m[b][o][c] + bias[o])
// Grid: (HW / (256*4), B). Each thread owns one float4 of pixels.
__global__ __launch_bounds__(256)
void conv_kernel(const float* __restrict__ x,     // (B, CIN, HW)
                 const float* __restrict__ m,     // (B, COUT, CIN)
                 const float* __restrict__ bias,  // (COUT,)
                 float* __restrict__ out)         // (B, COUT, HW)
{
    __shared__ float sm[COUT * CIN];   // 6 KB: m for this b

    const int b = blockIdx.y;
    const float* mb = m + (size_t)b * COUT * CIN;
    for (int i = threadIdx.x; i < COUT * CIN; i += 256)
        sm[i] = mb[i];
    __syncthreads();

    const int pix = (blockIdx.x * 256 + threadIdx.x) * 4;
    const float* xb = x + (size_t)b * CIN * HW + pix;

    float a0x = 0.f, a0y = 0.f, a0z = 0.f, a0w = 0.f;
    float a1x = 0.f, a1y = 0.f, a1z = 0.f, a1w = 0.f;
    float a2x = 0.f, a2y = 0.f, a2z = 0.f, a2w = 0.f;

    for (int c4 = 0; c4 < CIN; c4 += 4) {
        // broadcast LDS reads, merged to ds_read_b128 (conflict-free)
        const float4 m0 = *(const float4*)&sm[c4];
        const float4 m1 = *(const float4*)&sm[CIN + c4];
        const float4 m2 = *(const float4*)&sm[2 * CIN + c4];
        const float m0a[4] = {m0.x, m0.y, m0.z, m0.w};
        const float m1a[4] = {m1.x, m1.y, m1.z, m1.w};
        const float m2a[4] = {m2.x, m2.y, m2.z, m2.w};
#pragma unroll
        for (int j = 0; j < 4; ++j) {
            const float4 xv = *(const float4*)(xb + (size_t)(c4 + j) * HW);
            const float c0 = m0a[j], c1 = m1a[j], c2 = m2a[j];
            a0x = fmaf(xv.x, c0, a0x); a0y = fmaf(xv.y, c0, a0y);
            a0z = fmaf(xv.z, c0, a0z); a0w = fmaf(xv.w, c0, a0w);
            a1x = fmaf(xv.x, c1, a1x); a1y = fmaf(xv.y, c1, a1y);
            a1z = fmaf(xv.z, c1, a1z); a1w = fmaf(xv.w, c1, a1w);
            a2x = fmaf(xv.x, c2, a2x); a2y = fmaf(xv.y, c2, a2y);
            a2z = fmaf(xv.z, c2, a2z); a2w = fmaf(xv.w, c2, a2w);
        }
    }

    const float b0 = bias[0], b1 = bias[1], b2 = bias[2];
    auto clampv = [](float v) {
        return fminf(fmaxf(v, -CLAMP_V), CLAMP_V);
    };

    float* ob = out + ((size_t)b * COUT) * HW + pix;
    float4 o0 = {clampv(a0x + b0), clampv(a0y + b0), clampv(a0z + b0), clampv(a0w + b0)};
    float4 o1 = {clampv(a1x + b1), clampv(a1y + b1), clampv(a1z + b1), clampv(a1w + b1)};
    float4 o2 = {clampv(a2x + b2), clampv(a2y + b2), clampv(a2z + b2), clampv(a2w + b2)};
    *(float4*)(ob)          = o0;
    *(float4*)(ob + HW)     = o1;
    *(float4*)(ob + 2 * HW) = o2;
}

extern "C" void kernel_launch(void* const* d_in, const int* in_sizes, int n_in,
                              void* d_out, int out_size, void* d_ws, size_t ws_size,
                              hipStream_t stream) {
    const float* x        = (const float*)d_in[0];  // (B, CIN, H, W)
    const float* w        = (const float*)d_in[1];  // (B, WDIM)
    const float* weight   = (const float*)d_in[2];  // (COUT, CIN, 1, 1)
    const float* bias     = (const float*)d_in[3];  // (COUT,)
    const float* affine_w = (const float*)d_in[4];  // (CIN, WDIM)
    const float* affine_b = (const float*)d_in[5];  // (CIN,)
    float* out = (float*)d_out;
    float* m   = (float*)d_ws;                      // B*COUT*CIN floats = 48 KB

    // Kernel 1: one wave per (b,c) -> B*CIN waves = 4096 -> 1024 blocks of 256
    const int waves = B_ * CIN;
    styles_kernel<<<dim3(waves * 64 / 256), dim3(256), 0, stream>>>(
        w, weight, affine_b, affine_w, m);

    // Kernel 2: grid (HW/(256*4), B)
    conv_kernel<<<dim3(HW / (256 * 4), B_), dim3(256), 0, stream>>>(
        x, m, bias, out);
}